// Round 19
// baseline (14890.553 us; speedup 1.0000x reference)
//
#include <hip/hip_runtime.h>
#include <hip/hip_bf16.h>

#define T_LEN 1024
#define NB    32
#define DD    512
#define HH    512
#define EPS_  1e-5f

typedef unsigned short u16;
typedef unsigned int   u32;
typedef unsigned long long u64;
typedef float  f32x16 __attribute__((ext_vector_type(16)));
typedef short  bf16x8 __attribute__((ext_vector_type(8)));

__device__ __forceinline__ u16 f2bf(float f) {
    union { float f; u32 u; } cv; cv.f = f;
    u32 r = cv.u + 0x7FFFu + ((cv.u >> 16) & 1u);   // RNE
    return (u16)(r >> 16);
}
__device__ __forceinline__ float fsig(float x) {
    return 1.0f / (1.0f + __expf(-x));
}
__device__ __forceinline__ float ftanh(float x) {
    float ax = fabsf(x);
    float e  = __expf(-2.0f * ax);
    float t  = (1.0f - e) / (1.0f + e);
    return copysignf(t, x);
}
__device__ __forceinline__ int lds_load(int* p) {
    return __hip_atomic_load(p, __ATOMIC_ACQUIRE, __HIP_MEMORY_SCOPE_WORKGROUP);
}
__device__ __forceinline__ int lds_add_release(int* p) {
    return __hip_atomic_fetch_add(p, 1, __ATOMIC_RELEASE, __HIP_MEMORY_SCOPE_WORKGROUP);
}

// ---------------- LayerNorm: x[T,B,D] f32 -> xn bf16 ----------------
__global__ __launch_bounds__(256) void ln_kernel(const float* __restrict__ x,
                                                 const float* __restrict__ gamma,
                                                 const float* __restrict__ beta,
                                                 u16* __restrict__ xn) {
    int wave = threadIdx.x >> 6, lane = threadIdx.x & 63;
    long row = (long)blockIdx.x * 4 + wave;              // 0..T*B-1
    const float* xr = x + row * DD;
    int c0 = lane * 8;
    float4 v0 = *(const float4*)(xr + c0);
    float4 v1 = *(const float4*)(xr + c0 + 4);
    float s = v0.x+v0.y+v0.z+v0.w + v1.x+v1.y+v1.z+v1.w;
    float q = v0.x*v0.x+v0.y*v0.y+v0.z*v0.z+v0.w*v0.w
            + v1.x*v1.x+v1.y*v1.y+v1.z*v1.z+v1.w*v1.w;
    #pragma unroll
    for (int m = 1; m < 64; m <<= 1) { s += __shfl_xor(s, m); q += __shfl_xor(q, m); }
    float mu  = s * (1.0f / DD);
    float var = q * (1.0f / DD) - mu * mu;
    float rs  = rsqrtf(var + EPS_);
    float4 g0 = *(const float4*)(gamma + c0), g1 = *(const float4*)(gamma + c0 + 4);
    float4 b0 = *(const float4*)(beta  + c0), b1 = *(const float4*)(beta  + c0 + 4);
    float o[8];
    o[0]=(v0.x-mu)*rs*g0.x+b0.x; o[1]=(v0.y-mu)*rs*g0.y+b0.y;
    o[2]=(v0.z-mu)*rs*g0.z+b0.z; o[3]=(v0.w-mu)*rs*g0.w+b0.w;
    o[4]=(v1.x-mu)*rs*g1.x+b1.x; o[5]=(v1.y-mu)*rs*g1.y+b1.y;
    o[6]=(v1.z-mu)*rs*g1.z+b1.z; o[7]=(v1.w-mu)*rs*g1.w+b1.w;
    uint4 pk;
    pk.x = (u32)f2bf(o[0]) | ((u32)f2bf(o[1]) << 16);
    pk.y = (u32)f2bf(o[2]) | ((u32)f2bf(o[3]) << 16);
    pk.z = (u32)f2bf(o[4]) | ((u32)f2bf(o[5]) << 16);
    pk.w = (u32)f2bf(o[6]) | ((u32)f2bf(o[7]) << 16);
    *(uint4*)(xn + row * DD + c0) = pk;
}

// ---------------- prep: W->bf16, bias combine, init data+sentinels ----------------
__global__ __launch_bounds__(256) void prep_kernel(
        const float* __restrict__ wih_f, const float* __restrict__ whh_f,
        const float* __restrict__ bih_f, const float* __restrict__ bhh_f,
        const float* __restrict__ wih_b, const float* __restrict__ whh_b,
        const float* __restrict__ bih_b, const float* __restrict__ bhh_b,
        u16* __restrict__ Wc, float* __restrict__ biasC,
        u64* __restrict__ data, int* __restrict__ sent) {
    long i0 = (long)blockIdx.x * 256 + threadIdx.x;
    long stride = (long)gridDim.x * 256;
    for (long idx = i0; idx < 4194304L; idx += stride) {
        int m = (int)(idx >> 20); int off = (int)(idx & 1048575L);
        const float* src = (m == 0) ? wih_f : (m == 1) ? whh_f : (m == 2) ? wih_b : whh_b;
        Wc[idx] = f2bf(src[off]);
        if (idx < 4096L) {
            int d = (int)(idx >> 11), n = (int)(idx & 2047L);
            biasC[idx] = d ? (bih_b[n] + bhh_b[n]) : (bih_f[n] + bhh_f[n]);
        }
        if (idx < 16384L) data[idx] = 0;                   // h = 0
        if (idx < 128L)   sent[idx] = -1;                  // MUST reset each call (replays)
    }
}

// ---------------- epilogue: out += bf16(hist_b) ----------------
__global__ __launch_bounds__(256) void add_kernel(float* __restrict__ out,
                                                  const u16* __restrict__ hist) {
    long i0 = (long)blockIdx.x * 256 + threadIdx.x;
    long stride = (long)gridDim.x * 256;
    const ushort4* h4 = (const ushort4*)hist;
    float4* o4 = (float4*)out;
    for (long i = i0; i < 4194304L; i += stride) {
        float4 o = o4[i];
        ushort4 h = h4[i];
        o.x += __uint_as_float((u32)h.x << 16);
        o.y += __uint_as_float((u32)h.y << 16);
        o.z += __uint_as_float((u32)h.z << 16);
        o.w += __uint_as_float((u32)h.w << 16);
        o4[i] = o;
    }
}

// ---------------- persistent bidirectional LSTM scan, merged 1024-thread blocks ----
// 16 blocks: block = dir*8 + wg2 (8 blocks/dir). 16 waves: w0-7 x-group, w8-15 h-group.
// R17 decoupled structure (proven, 4.77ms) with WG pairs merged:
//  - straggler population 16 -> 8 per dir; xn tile fetched once per merged block
//    (total xn + bulk-read transactions HALVED, R8 law); per-BLOCK aggregated
//    sentinel (LDS counter, 8th wave stores) -> g0 polls 8 words/dir, not 64.
// Wave-col index C3 = wg2*8 + gw (gw = w&7) owns j-cols C3*8..C3*8+7, all 4 gates.
// Protocol identical: publish packets P=C3*64+bcol*2+hi -> vmcnt ack -> block
// sentinel; consumer g0 polls sentinels (relay via LDS); exactly-once bulk read.
#define SMEM_BYTES 131104
__global__ __launch_bounds__(1024) void scan_kernel(
        const u16* __restrict__ xn, const u16* __restrict__ Wc,
        const float* __restrict__ biasC, u64* __restrict__ data,
        int* __restrict__ sent, float* __restrict__ out, u16* __restrict__ hist) {
    extern __shared__ char smem_raw[];
    u16*   xn_lds = (u16*)smem_raw;            // [32][512] bf16, swizzled (x only)
    u16*   h_lds  = xn_lds + 16384;            // [32][512] bf16, swizzled (h only)
    float* accx   = (float*)(h_lds + 16384);   // [2][8][16*64] gx+bias (x -> h)
    int*   ctr    = (int*)(accx + 16384);      // [0]=xbar [1]=xcnt [2]=hbar [3]=hcnt
                                               // [4]=h_flag [5]=pubcnt

    const int wg2  = blockIdx.x & 7;
    const int dir  = blockIdx.x >> 3;
    const int w    = threadIdx.x >> 6;
    const int lane = threadIdx.x & 63;
    const bool is_x = (w < 8);
    const int gw   = w & 7;
    const int C3   = wg2 * 8 + gw;             // wave-col 0..63 within dir
    const int bcol = lane & 31;
    const int hi   = lane >> 5;
    const int hi8  = hi * 8;
    const int swz  = (bcol & 7) << 3;          // u16-unit swizzle
    const int tid8 = gw * 64 + lane;           // 0..511 within x- or h-group

    // A fragments: row r <-> W row (r>>3)*512 + C3*8 + (r&7)
    bf16x8 afrag[32];
    {
        int rowA = lane & 31;
        const u16* Wm = Wc + (size_t)(dir * 2 + (is_x ? 0 : 1)) * (2048 * 512)
                      + (size_t)((rowA >> 3) * 512 + C3 * 8 + (rowA & 7)) * 512 + hi8;
        #pragma unroll 32
        for (int kc = 0; kc < 32; kc++) afrag[kc] = *(const bf16x8*)(Wm + kc * 16);
    }
    float bias_r[16];
    if (is_x) {
        #pragma unroll 16
        for (int r = 0; r < 16; r++)
            bias_r[r] = biasC[dir * 2048 + (r >> 2) * 512 + C3 * 8 + (r & 3) + 4 * hi];
    }
    if (threadIdx.x == 0) {
        ctr[0] = 0; ctr[1] = 0; ctr[2] = 0; ctr[3] = 0; ctr[4] = -1; ctr[5] = 0;
    }
    __syncthreads();                            // the ONLY block-wide barrier

    if (is_x) {
        // =================== x-group: free-running gx producer ===================
        bf16x8 xpre[4];
        {   // direct-load tile 0 (512 lanes x 4 x 16B = 32KB)
            const u16* src = xn + (size_t)(dir ? (T_LEN - 1) : 0) * (NB * DD);
            #pragma unroll 4
            for (int r = 0; r < 4; r++)
                xpre[r] = *(const bf16x8*)(src + (tid8 + 512 * r) * 8);
        }
        int kbar = 0;
        #pragma unroll 1
        for (int i = 0; i < T_LEN; ++i) {
            if (i >= 2) {                       // accx[i&1] consumed? (h at sg=i-2)
                long gg = 2000000000L;
                while (lds_load(&ctr[3]) < 8 * (i - 1) && --gg > 0) {}
            }
            // xbarA: all x-waves done MFMA-reading xn_lds from iter i-1
            if (lane == 0) (void)lds_add_release(&ctr[0]);
            kbar++;
            { long gg = 2000000000L;
              while (lds_load(&ctr[0]) < 8 * kbar && --gg > 0) {} }
            #pragma unroll 4
            for (int r = 0; r < 4; r++) {       // commit tile i
                int u = (tid8 + 512 * r) * 8;
                int b = u >> 9, cu = u & 511;
                *(bf16x8*)(xn_lds + b * 512 + (cu ^ ((b & 7) << 3))) = xpre[r];
            }
            // xbarB: commit visible to all x-waves
            if (lane == 0) (void)lds_add_release(&ctr[0]);
            kbar++;
            { long gg = 2000000000L;
              while (lds_load(&ctr[0]) < 8 * kbar && --gg > 0) {} }
            if (i + 1 < T_LEN) {                // prefetch tile i+1
                const u16* src = xn + (size_t)(dir ? (T_LEN - 2 - i) : (i + 1)) * (NB * DD);
                #pragma unroll 4
                for (int r = 0; r < 4; r++)
                    xpre[r] = *(const bf16x8*)(src + (tid8 + 512 * r) * 8);
            }
            f32x16 a0, a1;
            #pragma unroll 16
            for (int r = 0; r < 16; r++) { a0[r] = 0.f; a1[r] = 0.f; }
            #pragma unroll 16
            for (int k2 = 0; k2 < 16; k2++) {
                bf16x8 b0 = *(const bf16x8*)(xn_lds + bcol * 512 + (((2*k2  )*16 + hi8) ^ swz));
                bf16x8 b1 = *(const bf16x8*)(xn_lds + bcol * 512 + (((2*k2+1)*16 + hi8) ^ swz));
                a0 = __builtin_amdgcn_mfma_f32_32x32x16_bf16(afrag[2*k2],   b0, a0, 0, 0, 0);
                a1 = __builtin_amdgcn_mfma_f32_32x32x16_bf16(afrag[2*k2+1], b1, a1, 0, 0, 0);
            }
            float* dst = accx + (i & 1) * 8192 + gw * 1024;
            #pragma unroll 16
            for (int r = 0; r < 16; r++) dst[r * 64 + lane] = a0[r] + a1[r] + bias_r[r];
            if (lane == 0) (void)lds_add_release(&ctr[1]); // xcnt: accx(i) ready
        }
    } else {
        // =================== h-group: pure recurrence chain ======================
        float c_st[4] = {0.f, 0.f, 0.f, 0.f};
        // pre-stage h(-1) = 0: 512 lanes x 32 u16
        #pragma unroll 4
        for (int k = 0; k < 4; k++)
            *(uint4*)(h_lds + tid8 * 32 + k * 8) = uint4{0, 0, 0, 0};
        int kh = 0;
        if (lane == 0) (void)lds_add_release(&ctr[2]);
        kh++;
        { long gg = 2000000000L;
          while (lds_load(&ctr[2]) < 8 * kh && --gg > 0) {} }

        #pragma unroll 1
        for (int sg = 0; sg < T_LEN; ++sg) {
            if (sg >= 1) {
                // detect h(sg-1): wave 8 polls the 8 per-block sentinels of this dir
                if (gw == 0) {
                    const int* sp = sent + dir * 8 + (lane & 7);
                    int rounds = 0, guard = 600000;
                    while (true) {
                        int v = __hip_atomic_load(sp, __ATOMIC_RELAXED,
                                                  __HIP_MEMORY_SCOPE_AGENT);
                        if (__all(v >= sg - 1) || --guard == 0) break;
                        if (++rounds > 4) __builtin_amdgcn_s_sleep(1);
                    }
                    __hip_atomic_store(&ctr[4], sg - 1, __ATOMIC_RELEASE,
                                       __HIP_MEMORY_SCOPE_WORKGROUP);
                } else {
                    long gg = 2000000000L;
                    while (__hip_atomic_load(&ctr[4], __ATOMIC_ACQUIRE,
                                             __HIP_MEMORY_SCOPE_WORKGROUP) < sg - 1
                           && --gg > 0) {}
                }
                // bulk read h(sg-1): 512 lanes x 4 coalesced 16B regions
                const char* bp = (const char*)(data + (size_t)(dir * 2 + ((sg - 1) & 1)) * 4096)
                               + (size_t)tid8 * 16;
                uint4 dq[4];
                #pragma unroll 4
                for (int n = 0; n < 4; n++) {
                    const char* ap = bp + n * 8192;
                    uint4 v;
                    asm volatile("global_load_dwordx4 %0, %1, off sc0 sc1"
                                 : "=&v"(v) : "v"(ap));
                    dq[n] = v;
                }
                asm volatile("s_waitcnt vmcnt(0)" ::: "memory");
                __builtin_amdgcn_sched_barrier(0);
                // stage: region m = tid8 + 512n -> row b = m&31 = tid8&31,
                // j0 = (m>>5)*8 = (tid8>>5 + 16n)*8, one b128 store
                int b  = tid8 & 31;
                int q  = tid8 >> 5;             // 0..15
                int sw = (b & 7) << 3;
                u16* hr = h_lds + b * 512;
                #pragma unroll 4
                for (int n = 0; n < 4; n++) {
                    int j = (q + 16 * n) * 8;
                    *(bf16x8*)(hr + (j ^ sw)) = *(const bf16x8*)&dq[n];
                }
                // hbar: all stages visible before MFMA
                if (lane == 0) (void)lds_add_release(&ctr[2]);
                kh++;
                { long gg = 2000000000L;
                  while (lds_load(&ctr[2]) < 8 * kh && --gg > 0) {} }
            }
            // h-matvec on h(sg-1)
            f32x16 a0, a1;
            #pragma unroll 16
            for (int r = 0; r < 16; r++) { a0[r] = 0.f; a1[r] = 0.f; }
            if (sg >= 1) {
                #pragma unroll 16
                for (int k2 = 0; k2 < 16; k2++) {
                    bf16x8 b0 = *(const bf16x8*)(h_lds + bcol * 512 + (((2*k2  )*16 + hi8) ^ swz));
                    bf16x8 b1 = *(const bf16x8*)(h_lds + bcol * 512 + (((2*k2+1)*16 + hi8) ^ swz));
                    a0 = __builtin_amdgcn_mfma_f32_32x32x16_bf16(afrag[2*k2],   b0, a0, 0, 0, 0);
                    a1 = __builtin_amdgcn_mfma_f32_32x32x16_bf16(afrag[2*k2+1], b1, a1, 0, 0, 0);
                }
            }
            // wait accx(sg) ready (x runs ahead: usually immediate)
            { long gg = 2000000000L;
              while (lds_load(&ctr[1]) < 8 * (sg + 1) && --gg > 0) {} }
            const float* ax = accx + (sg & 1) * 8192 + gw * 1024;
            float hv[4];
            #pragma unroll 4
            for (int m = 0; m < 4; m++) {
                float gi = a0[m]      + a1[m]      + ax[(m     ) * 64 + lane];
                float gf = a0[4 + m]  + a1[4 + m]  + ax[(4 + m ) * 64 + lane];
                float gg_= a0[8 + m]  + a1[8 + m]  + ax[(8 + m ) * 64 + lane];
                float go = a0[12 + m] + a1[12 + m] + ax[(12 + m) * 64 + lane];
                float ig = fsig(gi), fg = fsig(gf), gv = ftanh(gg_), og = fsig(go);
                float c = fg * c_st[m] + ig * gv;
                c_st[m] = c;
                hv[m] = og * ftanh(c);
            }
            if (lane == 0) (void)lds_add_release(&ctr[3]);  // hcnt: accx(sg) consumed
            u64 pk = (u64)f2bf(hv[0]) | ((u64)f2bf(hv[1]) << 16)
                   | ((u64)f2bf(hv[2]) << 32) | ((u64)f2bf(hv[3]) << 48);
            if (sg < T_LEN - 1) {
                // publish: packet P = C3*64 + bcol*2 + hi; ack; block sentinel
                u64* dp = data + (size_t)(dir * 2 + (sg & 1)) * 4096
                        + (size_t)(C3 * 64 + bcol * 2 + hi);
                __hip_atomic_store(dp, pk, __ATOMIC_RELAXED, __HIP_MEMORY_SCOPE_AGENT);
                asm volatile("s_waitcnt vmcnt(0)" ::: "memory");
                if (lane == 0) {
                    int prev = lds_add_release(&ctr[5]);
                    if ((prev & 7) == 7)        // 8th wave of this block for step sg
                        __hip_atomic_store(sent + dir * 8 + wg2, sg,
                                           __ATOMIC_RELAXED, __HIP_MEMORY_SCOPE_AGENT);
                }
            }
            // out/hist from registers (after sentinel: acks drain under next bulk RT)
            int tph = dir ? (T_LEN - 1 - sg) : sg;
            int jq  = C3 * 8 + 4 * hi;
            if (dir == 0) {
                float4 o4v = make_float4(hv[0], hv[1], hv[2], hv[3]);
                *(float4*)(out + ((size_t)tph * NB + bcol) * HH + jq) = o4v;
            } else {
                *(u64*)(hist + ((size_t)tph * NB + bcol) * HH + jq) = pk;
            }
        }
    }
}

extern "C" void kernel_launch(void* const* d_in, const int* in_sizes, int n_in,
                              void* d_out, int out_size, void* d_ws, size_t ws_size,
                              hipStream_t stream) {
    const float* x     = (const float*)d_in[0];
    const float* gamma = (const float*)d_in[1];
    const float* beta  = (const float*)d_in[2];
    const float* wih_f = (const float*)d_in[3];
    const float* whh_f = (const float*)d_in[4];
    const float* bih_f = (const float*)d_in[5];
    const float* bhh_f = (const float*)d_in[6];
    const float* wih_b = (const float*)d_in[7];
    const float* whh_b = (const float*)d_in[8];
    const float* bih_b = (const float*)d_in[9];
    const float* bhh_b = (const float*)d_in[10];
    float* out = (float*)d_out;

    u16*   xn    = (u16*)d_ws;                  // 32MB
    u16*   Wc    = xn + 16777216;               // 8MB
    float* biasC = (float*)(Wc + 4194304);      // 16KB
    u64*   data  = (u64*)(biasC + 4096);        // 16384 u64 = 128KB (2dir x 2slot x 4096)
    int*   sent  = (int*)(data + 16384);        // 128 ints (16 used)
    u16*   hist  = (u16*)(sent + 128);          // 32MB

    (void)hipFuncSetAttribute((const void*)scan_kernel,
                              hipFuncAttributeMaxDynamicSharedMemorySize, SMEM_BYTES);

    ln_kernel<<<dim3(8192), dim3(256), 0, stream>>>(x, gamma, beta, xn);
    prep_kernel<<<dim3(4096), dim3(256), 0, stream>>>(wih_f, whh_f, bih_f, bhh_f,
                                                      wih_b, whh_b, bih_b, bhh_b,
                                                      Wc, biasC, data, sent);
    scan_kernel<<<dim3(16), dim3(1024), SMEM_BYTES, stream>>>(xn, Wc, biasC, data,
                                                              sent, out, hist);
    add_kernel<<<dim3(2048), dim3(256), 0, stream>>>(out, hist);
}

// Round 20
// 4747.458 us; speedup vs baseline: 3.1365x; 3.1365x over previous
//
#include <hip/hip_runtime.h>
#include <hip/hip_bf16.h>

#define T_LEN 1024
#define NB    32
#define DD    512
#define HH    512
#define EPS_  1e-5f

typedef unsigned short u16;
typedef unsigned int   u32;
typedef unsigned long long u64;
typedef float  f32x16 __attribute__((ext_vector_type(16)));
typedef short  bf16x8 __attribute__((ext_vector_type(8)));

__device__ __forceinline__ u16 f2bf(float f) {
    union { float f; u32 u; } cv; cv.f = f;
    u32 r = cv.u + 0x7FFFu + ((cv.u >> 16) & 1u);   // RNE
    return (u16)(r >> 16);
}
__device__ __forceinline__ float fsig(float x) {
    return 1.0f / (1.0f + __expf(-x));
}
__device__ __forceinline__ float ftanh(float x) {
    float ax = fabsf(x);
    float e  = __expf(-2.0f * ax);
    float t  = (1.0f - e) / (1.0f + e);
    return copysignf(t, x);
}
__device__ __forceinline__ int lds_load(int* p) {
    return __hip_atomic_load(p, __ATOMIC_ACQUIRE, __HIP_MEMORY_SCOPE_WORKGROUP);
}
__device__ __forceinline__ void lds_add_release(int* p) {
    __hip_atomic_fetch_add(p, 1, __ATOMIC_RELEASE, __HIP_MEMORY_SCOPE_WORKGROUP);
}

// ---------------- LayerNorm: x[T,B,D] f32 -> xn bf16 ----------------
__global__ __launch_bounds__(256) void ln_kernel(const float* __restrict__ x,
                                                 const float* __restrict__ gamma,
                                                 const float* __restrict__ beta,
                                                 u16* __restrict__ xn) {
    int wave = threadIdx.x >> 6, lane = threadIdx.x & 63;
    long row = (long)blockIdx.x * 4 + wave;              // 0..T*B-1
    const float* xr = x + row * DD;
    int c0 = lane * 8;
    float4 v0 = *(const float4*)(xr + c0);
    float4 v1 = *(const float4*)(xr + c0 + 4);
    float s = v0.x+v0.y+v0.z+v0.w + v1.x+v1.y+v1.z+v1.w;
    float q = v0.x*v0.x+v0.y*v0.y+v0.z*v0.z+v0.w*v0.w
            + v1.x*v1.x+v1.y*v1.y+v1.z*v1.z+v1.w*v1.w;
    #pragma unroll
    for (int m = 1; m < 64; m <<= 1) { s += __shfl_xor(s, m); q += __shfl_xor(q, m); }
    float mu  = s * (1.0f / DD);
    float var = q * (1.0f / DD) - mu * mu;
    float rs  = rsqrtf(var + EPS_);
    float4 g0 = *(const float4*)(gamma + c0), g1 = *(const float4*)(gamma + c0 + 4);
    float4 b0 = *(const float4*)(beta  + c0), b1 = *(const float4*)(beta  + c0 + 4);
    float o[8];
    o[0]=(v0.x-mu)*rs*g0.x+b0.x; o[1]=(v0.y-mu)*rs*g0.y+b0.y;
    o[2]=(v0.z-mu)*rs*g0.z+b0.z; o[3]=(v0.w-mu)*rs*g0.w+b0.w;
    o[4]=(v1.x-mu)*rs*g1.x+b1.x; o[5]=(v1.y-mu)*rs*g1.y+b1.y;
    o[6]=(v1.z-mu)*rs*g1.z+b1.z; o[7]=(v1.w-mu)*rs*g1.w+b1.w;
    uint4 pk;
    pk.x = (u32)f2bf(o[0]) | ((u32)f2bf(o[1]) << 16);
    pk.y = (u32)f2bf(o[2]) | ((u32)f2bf(o[3]) << 16);
    pk.z = (u32)f2bf(o[4]) | ((u32)f2bf(o[5]) << 16);
    pk.w = (u32)f2bf(o[6]) | ((u32)f2bf(o[7]) << 16);
    *(uint4*)(xn + row * DD + c0) = pk;
}

// ---------------- prep: W->bf16, bias combine, init data+sentinels ----------------
__global__ __launch_bounds__(256) void prep_kernel(
        const float* __restrict__ wih_f, const float* __restrict__ whh_f,
        const float* __restrict__ bih_f, const float* __restrict__ bhh_f,
        const float* __restrict__ wih_b, const float* __restrict__ whh_b,
        const float* __restrict__ bih_b, const float* __restrict__ bhh_b,
        u16* __restrict__ Wc, float* __restrict__ biasC,
        u64* __restrict__ data, int* __restrict__ sent) {
    long i0 = (long)blockIdx.x * 256 + threadIdx.x;
    long stride = (long)gridDim.x * 256;
    for (long idx = i0; idx < 4194304L; idx += stride) {
        int m = (int)(idx >> 20); int off = (int)(idx & 1048575L);
        const float* src = (m == 0) ? wih_f : (m == 1) ? whh_f : (m == 2) ? wih_b : whh_b;
        Wc[idx] = f2bf(src[off]);
        if (idx < 4096L) {
            int d = (int)(idx >> 11), n = (int)(idx & 2047L);
            biasC[idx] = d ? (bih_b[n] + bhh_b[n]) : (bih_f[n] + bhh_f[n]);
        }
        if (idx < 16384L) data[idx] = 0;                   // h = 0
        if (idx < 128L)   sent[idx] = -1;                  // MUST reset each call (replays)
    }
}

// ---------------- epilogue: out += bf16(hist_b) ----------------
__global__ __launch_bounds__(256) void add_kernel(float* __restrict__ out,
                                                  const u16* __restrict__ hist) {
    long i0 = (long)blockIdx.x * 256 + threadIdx.x;
    long stride = (long)gridDim.x * 256;
    const ushort4* h4 = (const ushort4*)hist;
    float4* o4 = (float4*)out;
    for (long i = i0; i < 4194304L; i += stride) {
        float4 o = o4[i];
        ushort4 h = h4[i];
        o.x += __uint_as_float((u32)h.x << 16);
        o.y += __uint_as_float((u32)h.y << 16);
        o.z += __uint_as_float((u32)h.z << 16);
        o.w += __uint_as_float((u32)h.w << 16);
        o4[i] = o;
    }
}

// ---------------- persistent bidirectional LSTM scan, DECOUPLED wave groups -------
// R17 structure (proven best, 4.77ms). 32 blocks: block = (dir<<4)|wg. 8 waves:
// w0-3 x-group (free-running gx producer, 2-slot accx ring, LDS counter sync),
// w4-7 h-group (pure recurrence: detect -> bulk read -> stage -> hbar -> MFMA ->
// gates -> publish+ack+sentinel -> out/hist stores after sentinel so their acks
// drain under the next bulk-read's vmcnt wait). No block-wide barriers in loops.
// R19 tweak: g0 sentinel poll spins tight 4 rounds before s_sleep backoff.
// Geometry note (R18 post-mortem): 512 threads/block is FORCED -- afrag needs
// ~160 regs/wave (VGPR+AGPR); 1024-thread blocks cap at 128/wave -> spills.
#define SMEM_BYTES 98432
__global__ __launch_bounds__(512) void scan_kernel(
        const u16* __restrict__ xn, const u16* __restrict__ Wc,
        const float* __restrict__ biasC, u64* __restrict__ data,
        int* __restrict__ sent, float* __restrict__ out, u16* __restrict__ hist) {
    extern __shared__ char smem_raw[];
    u16*   xn_lds = (u16*)smem_raw;            // [32][512] bf16, swizzled (x only)
    u16*   h_lds  = xn_lds + 16384;            // [32][512] bf16, swizzled (h only)
    float* accx   = (float*)(h_lds + 16384);   // [2][4][16*64] gx+bias (x -> h)
    int*   ctr    = (int*)(accx + 8192);       // [0]=xbar [1]=xcnt [2]=hbar [3]=hcnt [4]=h_flag

    const int wg   = blockIdx.x & 15;
    const int dir  = blockIdx.x >> 4;
    const int w    = threadIdx.x >> 6;
    const int lane = threadIdx.x & 63;
    const bool is_x = (w < 4);
    const int g    = w & 3;
    const int bcol = lane & 31;
    const int hi   = lane >> 5;
    const int hi8  = hi * 8;
    const int swz  = (bcol & 7) << 3;          // u16-unit swizzle
    const int tid4 = (w & 3) * 64 + lane;      // 0..255 within x- or h-group

    // A fragments, remapped rows: row r <-> W row (r>>3)*512 + wg*32 + g*8 + (r&7)
    bf16x8 afrag[32];
    {
        int rowA = lane & 31;
        const u16* Wm = Wc + (size_t)(dir * 2 + (is_x ? 0 : 1)) * (2048 * 512)
                      + (size_t)((rowA >> 3) * 512 + wg * 32 + g * 8 + (rowA & 7)) * 512 + hi8;
        #pragma unroll 32
        for (int kc = 0; kc < 32; kc++) afrag[kc] = *(const bf16x8*)(Wm + kc * 16);
    }
    float bias_r[16];
    if (is_x) {
        #pragma unroll 16
        for (int r = 0; r < 16; r++)
            bias_r[r] = biasC[dir * 2048 + (r >> 2) * 512 + wg * 32 + g * 8 + (r & 3) + 4 * hi];
    }
    if (threadIdx.x == 0) {
        ctr[0] = 0; ctr[1] = 0; ctr[2] = 0; ctr[3] = 0; ctr[4] = -1;
    }
    __syncthreads();                            // the ONLY block-wide barrier

    if (is_x) {
        // =================== x-group: free-running gx producer ===================
        bf16x8 xpre[8];
        {   // direct-load tile 0
            const u16* src = xn + (size_t)(dir ? (T_LEN - 1) : 0) * (NB * DD);
            #pragma unroll 8
            for (int r = 0; r < 8; r++)
                xpre[r] = *(const bf16x8*)(src + (tid4 + 256 * r) * 8);
        }
        int kbar = 0;
        #pragma unroll 1
        for (int i = 0; i < T_LEN; ++i) {
            if (i >= 2) {                       // accx[i&1] consumed? (h at sg=i-2)
                long gg = 2000000000L;
                while (lds_load(&ctr[3]) < 4 * (i - 1) && --gg > 0) {}
            }
            // xbarA: everyone done MFMA-reading xn_lds from iter i-1
            if (lane == 0) lds_add_release(&ctr[0]);
            kbar++;
            { long gg = 2000000000L;
              while (lds_load(&ctr[0]) < 4 * kbar && --gg > 0) {} }
            #pragma unroll 8
            for (int r = 0; r < 8; r++) {       // commit tile i
                int u = (tid4 + 256 * r) * 8;
                int b = u >> 9, cu = u & 511;
                *(bf16x8*)(xn_lds + b * 512 + (cu ^ ((b & 7) << 3))) = xpre[r];
            }
            // xbarB: commit visible to all x-waves
            if (lane == 0) lds_add_release(&ctr[0]);
            kbar++;
            { long gg = 2000000000L;
              while (lds_load(&ctr[0]) < 4 * kbar && --gg > 0) {} }
            if (i + 1 < T_LEN) {                // prefetch tile i+1
                const u16* src = xn + (size_t)(dir ? (T_LEN - 2 - i) : (i + 1)) * (NB * DD);
                #pragma unroll 8
                for (int r = 0; r < 8; r++)
                    xpre[r] = *(const bf16x8*)(src + (tid4 + 256 * r) * 8);
            }
            f32x16 a0, a1;
            #pragma unroll 16
            for (int r = 0; r < 16; r++) { a0[r] = 0.f; a1[r] = 0.f; }
            #pragma unroll 16
            for (int k2 = 0; k2 < 16; k2++) {
                bf16x8 b0 = *(const bf16x8*)(xn_lds + bcol * 512 + (((2*k2  )*16 + hi8) ^ swz));
                bf16x8 b1 = *(const bf16x8*)(xn_lds + bcol * 512 + (((2*k2+1)*16 + hi8) ^ swz));
                a0 = __builtin_amdgcn_mfma_f32_32x32x16_bf16(afrag[2*k2],   b0, a0, 0, 0, 0);
                a1 = __builtin_amdgcn_mfma_f32_32x32x16_bf16(afrag[2*k2+1], b1, a1, 0, 0, 0);
            }
            float* dst = accx + (i & 1) * 4096 + g * 1024;
            #pragma unroll 16
            for (int r = 0; r < 16; r++) dst[r * 64 + lane] = a0[r] + a1[r] + bias_r[r];
            if (lane == 0) lds_add_release(&ctr[1]);       // xcnt: accx(i) ready
        }
    } else {
        // =================== h-group: pure recurrence chain ======================
        float c_st[4] = {0.f, 0.f, 0.f, 0.f};
        // pre-stage h(-1) = 0
        #pragma unroll 8
        for (int k = 0; k < 8; k++)
            *(uint4*)(h_lds + tid4 * 64 + k * 8) = uint4{0, 0, 0, 0};
        int kh = 0;
        if (lane == 0) lds_add_release(&ctr[2]);
        kh++;
        { long gg = 2000000000L;
          while (lds_load(&ctr[2]) < 4 * kh && --gg > 0) {} }

        #pragma unroll 1
        for (int sg = 0; sg < T_LEN; ++sg) {
            if (sg >= 1) {
                // detect h(sg-1): g0 polls global sentinels, relays via LDS flag
                if (g == 0) {
                    const int* sp = sent + dir * 64 + lane;
                    int rounds = 0, guard = 600000;
                    while (true) {
                        int v = __hip_atomic_load(sp, __ATOMIC_RELAXED,
                                                  __HIP_MEMORY_SCOPE_AGENT);
                        if (__all(v >= sg - 1) || --guard == 0) break;
                        if (++rounds > 4) __builtin_amdgcn_s_sleep(1);
                    }
                    __hip_atomic_store(&ctr[4], sg - 1, __ATOMIC_RELEASE,
                                       __HIP_MEMORY_SCOPE_WORKGROUP);
                } else {
                    long gg = 2000000000L;
                    while (__hip_atomic_load(&ctr[4], __ATOMIC_ACQUIRE,
                                             __HIP_MEMORY_SCOPE_WORKGROUP) < sg - 1
                           && --gg > 0) {}
                }
                // bulk read h(sg-1): 8 coalesced 16B regions per lane
                const char* bp = (const char*)(data + (size_t)(dir * 2 + ((sg - 1) & 1)) * 4096)
                               + (size_t)tid4 * 16;
                uint4 dq[8];
                #pragma unroll 8
                for (int n = 0; n < 8; n++) {
                    const char* ap = bp + n * 4096;
                    uint4 v;
                    asm volatile("global_load_dwordx4 %0, %1, off sc0 sc1"
                                 : "=&v"(v) : "v"(ap));
                    dq[n] = v;
                }
                asm volatile("s_waitcnt vmcnt(0)" ::: "memory");
                __builtin_amdgcn_sched_barrier(0);
                // stage: pair (512n+2t,+1) -> row b=t&31, j0=64n+8*(t>>5), one b128
                int b  = tid4 & 31;
                int qh = tid4 >> 5;
                int sw = (b & 7) << 3;
                u16* hr = h_lds + b * 512;
                #pragma unroll 8
                for (int n = 0; n < 8; n++) {
                    int j = 64 * n + 8 * qh;
                    *(bf16x8*)(hr + (j ^ sw)) = *(const bf16x8*)&dq[n];
                }
                // hbar: all stages visible before MFMA
                if (lane == 0) lds_add_release(&ctr[2]);
                kh++;
                { long gg = 2000000000L;
                  while (lds_load(&ctr[2]) < 4 * kh && --gg > 0) {} }
            }
            // h-matvec on h(sg-1)
            f32x16 a0, a1;
            #pragma unroll 16
            for (int r = 0; r < 16; r++) { a0[r] = 0.f; a1[r] = 0.f; }
            if (sg >= 1) {
                #pragma unroll 16
                for (int k2 = 0; k2 < 16; k2++) {
                    bf16x8 b0 = *(const bf16x8*)(h_lds + bcol * 512 + (((2*k2  )*16 + hi8) ^ swz));
                    bf16x8 b1 = *(const bf16x8*)(h_lds + bcol * 512 + (((2*k2+1)*16 + hi8) ^ swz));
                    a0 = __builtin_amdgcn_mfma_f32_32x32x16_bf16(afrag[2*k2],   b0, a0, 0, 0, 0);
                    a1 = __builtin_amdgcn_mfma_f32_32x32x16_bf16(afrag[2*k2+1], b1, a1, 0, 0, 0);
                }
            }
            // wait accx(sg) ready (x runs ahead: usually immediate)
            { long gg = 2000000000L;
              while (lds_load(&ctr[1]) < 4 * (sg + 1) && --gg > 0) {} }
            const float* ax = accx + (sg & 1) * 4096 + g * 1024;
            float hv[4];
            #pragma unroll 4
            for (int m = 0; m < 4; m++) {
                float gi = a0[m]      + a1[m]      + ax[(m     ) * 64 + lane];
                float gf = a0[4 + m]  + a1[4 + m]  + ax[(4 + m ) * 64 + lane];
                float gg_= a0[8 + m]  + a1[8 + m]  + ax[(8 + m ) * 64 + lane];
                float go = a0[12 + m] + a1[12 + m] + ax[(12 + m) * 64 + lane];
                float ig = fsig(gi), fg = fsig(gf), gv = ftanh(gg_), og = fsig(go);
                float c = fg * c_st[m] + ig * gv;
                c_st[m] = c;
                hv[m] = og * ftanh(c);
            }
            if (lane == 0) lds_add_release(&ctr[3]);       // hcnt: accx(sg) consumed
            u64 pk = (u64)f2bf(hv[0]) | ((u64)f2bf(hv[1]) << 16)
                   | ((u64)f2bf(hv[2]) << 32) | ((u64)f2bf(hv[3]) << 48);
            if (sg < T_LEN - 1) {
                // publish: packet P=(wg*4+g)*64+bcol*2+hi, ack, sentinel
                u64* dp = data + (size_t)(dir * 2 + (sg & 1)) * 4096
                        + (size_t)((wg * 4 + g) * 64 + bcol * 2 + hi);
                __hip_atomic_store(dp, pk, __ATOMIC_RELAXED, __HIP_MEMORY_SCOPE_AGENT);
                asm volatile("s_waitcnt vmcnt(0)" ::: "memory");
                if (lane == 0)
                    __hip_atomic_store(sent + dir * 64 + wg * 4 + g, sg,
                                       __ATOMIC_RELAXED, __HIP_MEMORY_SCOPE_AGENT);
            }
            // out/hist from registers (after sentinel: acks drain under next bulk RT)
            int tph = dir ? (T_LEN - 1 - sg) : sg;
            int jq  = wg * 32 + g * 8 + 4 * hi;            // j-quad base
            if (dir == 0) {
                float4 o4v = make_float4(hv[0], hv[1], hv[2], hv[3]);
                *(float4*)(out + ((size_t)tph * NB + bcol) * HH + jq) = o4v;
            } else {
                *(u64*)(hist + ((size_t)tph * NB + bcol) * HH + jq) = pk;
            }
        }
    }
}

extern "C" void kernel_launch(void* const* d_in, const int* in_sizes, int n_in,
                              void* d_out, int out_size, void* d_ws, size_t ws_size,
                              hipStream_t stream) {
    const float* x     = (const float*)d_in[0];
    const float* gamma = (const float*)d_in[1];
    const float* beta  = (const float*)d_in[2];
    const float* wih_f = (const float*)d_in[3];
    const float* whh_f = (const float*)d_in[4];
    const float* bih_f = (const float*)d_in[5];
    const float* bhh_f = (const float*)d_in[6];
    const float* wih_b = (const float*)d_in[7];
    const float* whh_b = (const float*)d_in[8];
    const float* bih_b = (const float*)d_in[9];
    const float* bhh_b = (const float*)d_in[10];
    float* out = (float*)d_out;

    u16*   xn    = (u16*)d_ws;                  // 32MB
    u16*   Wc    = xn + 16777216;               // 8MB
    float* biasC = (float*)(Wc + 4194304);      // 16KB
    u64*   data  = (u64*)(biasC + 4096);        // 16384 u64 = 128KB (2dir x 2slot x 4096)
    int*   sent  = (int*)(data + 16384);        // 128 ints
    u16*   hist  = (u16*)(sent + 128);          // 32MB

    (void)hipFuncSetAttribute((const void*)scan_kernel,
                              hipFuncAttributeMaxDynamicSharedMemorySize, SMEM_BYTES);

    ln_kernel<<<dim3(8192), dim3(256), 0, stream>>>(x, gamma, beta, xn);
    prep_kernel<<<dim3(4096), dim3(256), 0, stream>>>(wih_f, whh_f, bih_f, bhh_f,
                                                      wih_b, whh_b, bih_b, bhh_b,
                                                      Wc, biasC, data, sent);
    scan_kernel<<<dim3(32), dim3(512), SMEM_BYTES, stream>>>(xn, Wc, biasC, data,
                                                             sent, out, hist);
    add_kernel<<<dim3(2048), dim3(256), 0, stream>>>(out, hist);
}